// Round 4
// baseline (60.224 us; speedup 1.0000x reference)
//
#include <hip/hip_runtime.h>

// 2-level separable db4 DWT, pywt 'symmetric', fused, rolling-row version v4.
// x: (8, 512, 512, 16) f32 -> out: concat(aa, ad, da, dd), each (8, 259, 259, 16) f32.
//
// Grid: (col-band, row-segment, batch) = (9, 33, 8) = 2376 blocks, 256 thr.
// v4: raw s_barrier (lgkmcnt-only, NO vmcnt drain) so prefetched row-loads
// stay in flight across the barrier; LDS channel-rotate swizzle kills the
// 4-way ds_read_b128 bank conflict.

constexpr int N  = 512;
constexpr int ON = 259;          // (N + 8 - 1) / 2
constexpr int CH = 16;
constexpr int NB = 8;
constexpr int JB = 29;           // output cols per band
constexpr int BANDS = 9;         // 9*29 = 261 >= 259
constexpr int RS = 8;            // output rows per segment
constexpr int SEGS = 33;         // 33*8 = 264 >= 259
constexpr int W  = 2 * JB + 6;   // 64 input cols per band
constexpr int LSTR = 20;         // padded word stride per column

__device__ __forceinline__ int refl(int r) {
  r = (r < 0) ? (-r - 1) : r;
  return (r >= N) ? (2 * N - 1 - r) : r;
}

// Swizzled LDS word index for (column c, channel-word w in {0,4,8,12}).
// Rotation by 4*(c>>2) mod 16 keeps 16B alignment; banks for the stage-B
// read pattern become 2-way max (free).
__device__ __forceinline__ int lds_idx(int c, int w) {
  return c * LSTR + ((w + ((c >> 2) << 2)) & 15);
}

// Barrier with LDS-write visibility but WITHOUT draining vmcnt: global
// loads issued before it remain in flight (compiler waits at their use).
__device__ __forceinline__ void block_sync_lds() {
  asm volatile("s_waitcnt lgkmcnt(0)" ::: "memory");
  __builtin_amdgcn_s_barrier();
  __builtin_amdgcn_sched_barrier(0);
}

__global__ __launch_bounds__(256) void dwt2_ring(
    const float* __restrict__ x, const float* __restrict__ dec_lo,
    float* __restrict__ out)
{
  const int band = blockIdx.x, seg = blockIdx.y, b = blockIdx.z;
  const int j0 = band * JB;
  const int i0 = seg * RS;
  const int i1 = min(i0 + RS, ON);
  const int t  = threadIdx.x;
  const int tc = t >> 2;             // column within band (0..63)
  const int tch = (t & 3) << 2;      // channel word (0,4,8,12)

  __shared__ float a_buf[2][W * LSTR];  // 2 x 5 KB
  __shared__ float d_buf[2][W * LSTR];  // 2 x 5 KB

  float lo[8], hi[8];
#pragma unroll
  for (int m = 0; m < 8; ++m) lo[m] = dec_lo[7 - m];
#pragma unroll
  for (int m = 0; m < 8; ++m) hi[m] = (m & 1) ? -dec_lo[m] : dec_lo[m];

  const int gc = refl(2 * j0 - 6 + tc);
  const float* xb   = x + (size_t)b * N * N * CH;
  const float* colp = xb + (size_t)gc * CH + tch;

  auto ldrow = [&](int r) -> float4 {
    return *reinterpret_cast<const float4*>(colp + (size_t)refl(r) * (N * CH));
  };

  // Warm the 8-row register FIFO for output row i0.
  float4 f[8];
#pragma unroll
  for (int m = 0; m < 8; ++m) f[m] = ldrow(2 * i0 - 6 + m);

  // Stage-B mapping: threads 0..115 -> aa/ad from a_buf; 116..231 -> da/dd
  // from d_buf; 232..255 idle in stage B.
  const int  sb  = (t >= 116);
  const int  p   = sb ? (t - 116) : t;
  const int  jr  = p >> 2;
  const int  bch = (p & 3) << 2;
  const int  j   = j0 + jr;
  const bool wr  = (t < 232) && (j < ON);
  const size_t OUTSZ = (size_t)NB * ON * ON * CH;
  float* o_lo = out + (size_t)(2 * sb) * OUTSZ;   // aa or da
  float* o_hi = o_lo + OUTSZ;                     // ad or dd

  const int widx = lds_idx(tc, tch);

  int cur = 0;
  for (int i = i0; i < i1; ++i, cur ^= 1) {
    // ---- Stage A: vertical DWT from the register FIFO
    float4 av = {0.f, 0.f, 0.f, 0.f}, dv = {0.f, 0.f, 0.f, 0.f};
#pragma unroll
    for (int m = 0; m < 8; ++m) {
      av.x += lo[m] * f[m].x; av.y += lo[m] * f[m].y;
      av.z += lo[m] * f[m].z; av.w += lo[m] * f[m].w;
      dv.x += hi[m] * f[m].x; dv.y += hi[m] * f[m].y;
      dv.z += hi[m] * f[m].z; dv.w += hi[m] * f[m].w;
    }

    // Shift FIFO; issue next 2 row-loads (branchless — reflection keeps the
    // index valid even past the segment end). They stay in flight across
    // the raw barrier and their latency hides under stage B.
#pragma unroll
    for (int k = 0; k < 6; ++k) f[k] = f[k + 2];
    f[6] = ldrow(2 * i + 2);
    f[7] = ldrow(2 * i + 3);

    *reinterpret_cast<float4*>(&a_buf[cur][widx]) = av;
    *reinterpret_cast<float4*>(&d_buf[cur][widx]) = dv;

    block_sync_lds();

    // ---- Stage B: horizontal DWT from LDS -> 2 subbands per thread
    if (wr) {
      const float* src = sb ? d_buf[cur] : a_buf[cur];
      float4 aL = {0.f, 0.f, 0.f, 0.f}, aH = {0.f, 0.f, 0.f, 0.f};
#pragma unroll
      for (int m = 0; m < 8; ++m) {
        const float4 s = *reinterpret_cast<const float4*>(
            &src[lds_idx(2 * jr + m, bch)]);
        aL.x += lo[m] * s.x; aL.y += lo[m] * s.y;
        aL.z += lo[m] * s.z; aL.w += lo[m] * s.w;
        aH.x += hi[m] * s.x; aH.y += hi[m] * s.y;
        aH.z += hi[m] * s.z; aH.w += hi[m] * s.w;
      }
      const size_t o = (((size_t)b * ON + i) * ON + j) * CH + bch;
      *reinterpret_cast<float4*>(o_lo + o) = aL;
      *reinterpret_cast<float4*>(o_hi + o) = aH;
    }
    // No second barrier needed: buffer written at i+1 is buf[cur^1]; the
    // WAR on buf[cur] (rewritten at i+2) is separated by the i+1 barrier.
  }
}

extern "C" void kernel_launch(void* const* d_in, const int* in_sizes, int n_in,
                              void* d_out, int out_size, void* d_ws, size_t ws_size,
                              hipStream_t stream) {
  const float* x      = (const float*)d_in[0];
  const float* dec_lo = (const float*)d_in[1];
  float* out          = (float*)d_out;
  dim3 grid(BANDS, SEGS, NB);
  dwt2_ring<<<grid, 256, 0, stream>>>(x, dec_lo, out);
}

// Round 6
// 59.375 us; speedup vs baseline: 1.0143x; 1.0143x over previous
//
#include <hip/hip_runtime.h>

// 2-level separable db4 DWT, pywt 'symmetric', fused, rolling-row version v5b.
// x: (8, 512, 512, 16) f32 -> out: concat(aa, ad, da, dd), each (8, 259, 259, 16) f32.
//
// v5b = v4 + nontemporal subband stores (via native ext_vector_type for the
// builtin): output is write-once/never-read, so bypass cache allocation and
// keep the 134 MB input L3-resident (input+output = 271 MB > 256 MB IC).

constexpr int N  = 512;
constexpr int ON = 259;          // (N + 8 - 1) / 2
constexpr int CH = 16;
constexpr int NB = 8;
constexpr int JB = 29;           // output cols per band
constexpr int BANDS = 9;         // 9*29 = 261 >= 259
constexpr int RS = 8;            // output rows per segment
constexpr int SEGS = 33;         // 33*8 = 264 >= 259
constexpr int W  = 2 * JB + 6;   // 64 input cols per band
constexpr int LSTR = 20;         // padded word stride per column

typedef float vfloat4 __attribute__((ext_vector_type(4)));

__device__ __forceinline__ int refl(int r) {
  r = (r < 0) ? (-r - 1) : r;
  return (r >= N) ? (2 * N - 1 - r) : r;
}

__device__ __forceinline__ int lds_idx(int c, int w) {
  return c * LSTR + ((w + ((c >> 2) << 2)) & 15);
}

// Barrier with LDS-write visibility but WITHOUT draining vmcnt.
__device__ __forceinline__ void block_sync_lds() {
  asm volatile("s_waitcnt lgkmcnt(0)" ::: "memory");
  __builtin_amdgcn_s_barrier();
  __builtin_amdgcn_sched_barrier(0);
}

__device__ __forceinline__ void nt_store4(float* p, float4 v) {
  vfloat4 nv = {v.x, v.y, v.z, v.w};
  __builtin_nontemporal_store(nv, reinterpret_cast<vfloat4*>(p));
}

__global__ __launch_bounds__(256) void dwt2_ring(
    const float* __restrict__ x, const float* __restrict__ dec_lo,
    float* __restrict__ out)
{
  const int band = blockIdx.x, seg = blockIdx.y, b = blockIdx.z;
  const int j0 = band * JB;
  const int i0 = seg * RS;
  const int i1 = min(i0 + RS, ON);
  const int t  = threadIdx.x;
  const int tc = t >> 2;             // column within band (0..63)
  const int tch = (t & 3) << 2;      // channel word (0,4,8,12)

  __shared__ float a_buf[2][W * LSTR];  // 2 x 5 KB
  __shared__ float d_buf[2][W * LSTR];  // 2 x 5 KB

  float lo[8], hi[8];
#pragma unroll
  for (int m = 0; m < 8; ++m) lo[m] = dec_lo[7 - m];
#pragma unroll
  for (int m = 0; m < 8; ++m) hi[m] = (m & 1) ? -dec_lo[m] : dec_lo[m];

  const int gc = refl(2 * j0 - 6 + tc);
  const float* xb   = x + (size_t)b * N * N * CH;
  const float* colp = xb + (size_t)gc * CH + tch;

  auto ldrow = [&](int r) -> float4 {
    return *reinterpret_cast<const float4*>(colp + (size_t)refl(r) * (N * CH));
  };

  // Warm the 8-row register FIFO for output row i0.
  float4 f[8];
#pragma unroll
  for (int m = 0; m < 8; ++m) f[m] = ldrow(2 * i0 - 6 + m);

  // Stage-B mapping: threads 0..115 -> aa/ad from a_buf; 116..231 -> da/dd
  // from d_buf; 232..255 idle in stage B.
  const int  sb  = (t >= 116);
  const int  p   = sb ? (t - 116) : t;
  const int  jr  = p >> 2;
  const int  bch = (p & 3) << 2;
  const int  j   = j0 + jr;
  const bool wr  = (t < 232) && (j < ON);
  const size_t OUTSZ = (size_t)NB * ON * ON * CH;
  float* o_lo = out + (size_t)(2 * sb) * OUTSZ;   // aa or da
  float* o_hi = o_lo + OUTSZ;                     // ad or dd

  const int widx = lds_idx(tc, tch);

  int cur = 0;
  for (int i = i0; i < i1; ++i, cur ^= 1) {
    // ---- Stage A: vertical DWT from the register FIFO
    float4 av = {0.f, 0.f, 0.f, 0.f}, dv = {0.f, 0.f, 0.f, 0.f};
#pragma unroll
    for (int m = 0; m < 8; ++m) {
      av.x += lo[m] * f[m].x; av.y += lo[m] * f[m].y;
      av.z += lo[m] * f[m].z; av.w += lo[m] * f[m].w;
      dv.x += hi[m] * f[m].x; dv.y += hi[m] * f[m].y;
      dv.z += hi[m] * f[m].z; dv.w += hi[m] * f[m].w;
    }

    // Shift FIFO; issue next 2 row-loads (stay in flight across barrier).
#pragma unroll
    for (int k = 0; k < 6; ++k) f[k] = f[k + 2];
    f[6] = ldrow(2 * i + 2);
    f[7] = ldrow(2 * i + 3);

    *reinterpret_cast<float4*>(&a_buf[cur][widx]) = av;
    *reinterpret_cast<float4*>(&d_buf[cur][widx]) = dv;

    block_sync_lds();

    // ---- Stage B: horizontal DWT from LDS -> 2 subbands per thread
    if (wr) {
      const float* src = sb ? d_buf[cur] : a_buf[cur];
      float4 aL = {0.f, 0.f, 0.f, 0.f}, aH = {0.f, 0.f, 0.f, 0.f};
#pragma unroll
      for (int m = 0; m < 8; ++m) {
        const float4 s = *reinterpret_cast<const float4*>(
            &src[lds_idx(2 * jr + m, bch)]);
        aL.x += lo[m] * s.x; aL.y += lo[m] * s.y;
        aL.z += lo[m] * s.z; aL.w += lo[m] * s.w;
        aH.x += hi[m] * s.x; aH.y += hi[m] * s.y;
        aH.z += hi[m] * s.z; aH.w += hi[m] * s.w;
      }
      const size_t o = (((size_t)b * ON + i) * ON + j) * CH + bch;
      nt_store4(o_lo + o, aL);
      nt_store4(o_hi + o, aH);
    }
  }
}

extern "C" void kernel_launch(void* const* d_in, const int* in_sizes, int n_in,
                              void* d_out, int out_size, void* d_ws, size_t ws_size,
                              hipStream_t stream) {
  const float* x      = (const float*)d_in[0];
  const float* dec_lo = (const float*)d_in[1];
  float* out          = (float*)d_out;
  dim3 grid(BANDS, SEGS, NB);
  dwt2_ring<<<grid, 256, 0, stream>>>(x, dec_lo, out);
}

// Round 7
// 57.842 us; speedup vs baseline: 1.0412x; 1.0265x over previous
//
#include <hip/hip_runtime.h>

// 2-level separable db4 DWT, pywt 'symmetric', fused, rolling-row version v6.
// x: (8, 512, 512, 16) f32 -> out: concat(aa, ad, da, dd), each (8, 259, 259, 16) f32.
//
// v6: prefetch distance 2 iterations (10-row register FIFO), RS=16 with a
// constant trip count (fully unrolled -> register-renamed FIFO), fewer
// blocks but longer-lived (grid 9x17x8 = 1224).

constexpr int N  = 512;
constexpr int ON = 259;          // (N + 8 - 1) / 2
constexpr int CH = 16;
constexpr int NB = 8;
constexpr int JB = 29;           // output cols per band
constexpr int BANDS = 9;         // 9*29 = 261 >= 259
constexpr int RS = 16;           // output rows per segment (constant trip)
constexpr int SEGS = 17;         // 17*16 = 272 >= 259
constexpr int W  = 2 * JB + 6;   // 64 input cols per band
constexpr int LSTR = 20;         // padded word stride per column

typedef float vfloat4 __attribute__((ext_vector_type(4)));

__device__ __forceinline__ int refl(int r) {
  r = (r < 0) ? (-r - 1) : r;
  return (r >= N) ? (2 * N - 1 - r) : r;
}

__device__ __forceinline__ int lds_idx(int c, int w) {
  return c * LSTR + ((w + ((c >> 2) << 2)) & 15);
}

// Barrier with LDS-write visibility but WITHOUT draining vmcnt.
__device__ __forceinline__ void block_sync_lds() {
  asm volatile("s_waitcnt lgkmcnt(0)" ::: "memory");
  __builtin_amdgcn_s_barrier();
  __builtin_amdgcn_sched_barrier(0);
}

__device__ __forceinline__ void nt_store4(float* p, float4 v) {
  vfloat4 nv = {v.x, v.y, v.z, v.w};
  __builtin_nontemporal_store(nv, reinterpret_cast<vfloat4*>(p));
}

__global__ __launch_bounds__(256) void dwt2_ring(
    const float* __restrict__ x, const float* __restrict__ dec_lo,
    float* __restrict__ out)
{
  const int band = blockIdx.x, seg = blockIdx.y, b = blockIdx.z;
  const int j0 = band * JB;
  const int i0 = seg * RS;
  const int t  = threadIdx.x;
  const int tc = t >> 2;             // column within band (0..63)
  const int tch = (t & 3) << 2;      // channel word (0,4,8,12)

  __shared__ float a_buf[2][W * LSTR];  // 2 x 5 KB
  __shared__ float d_buf[2][W * LSTR];  // 2 x 5 KB

  float lo[8], hi[8];
#pragma unroll
  for (int m = 0; m < 8; ++m) lo[m] = dec_lo[7 - m];
#pragma unroll
  for (int m = 0; m < 8; ++m) hi[m] = (m & 1) ? -dec_lo[m] : dec_lo[m];

  const int gc = refl(2 * j0 - 6 + tc);
  const float* xb   = x + (size_t)b * N * N * CH;
  const float* colp = xb + (size_t)gc * CH + tch;

  auto ldrow = [&](int r) -> float4 {
    return *reinterpret_cast<const float4*>(colp + (size_t)refl(r) * (N * CH));
  };

  // 10-row register FIFO: f[k] holds input row 2i-6+k (k=0..9).
  float4 f[10];
#pragma unroll
  for (int m = 0; m < 10; ++m) f[m] = ldrow(2 * i0 - 6 + m);

  // Stage-B mapping: threads 0..115 -> aa/ad from a_buf; 116..231 -> da/dd
  // from d_buf; 232..255 idle in stage B.
  const int  sb  = (t >= 116);
  const int  p   = sb ? (t - 116) : t;
  const int  jr  = p >> 2;
  const int  bch = (p & 3) << 2;
  const int  j   = j0 + jr;
  const bool wr  = (t < 232) && (j < ON);
  const size_t OUTSZ = (size_t)NB * ON * ON * CH;
  float* o_lo = out + (size_t)(2 * sb) * OUTSZ;   // aa or da
  float* o_hi = o_lo + OUTSZ;                     // ad or dd

  const int widx = lds_idx(tc, tch);

#pragma unroll
  for (int it = 0; it < RS; ++it) {
    const int i = i0 + it;
    const int cur = it & 1;

    // ---- Stage A: vertical DWT from the register FIFO (rows 2i-6..2i+1)
    float4 av = {0.f, 0.f, 0.f, 0.f}, dv = {0.f, 0.f, 0.f, 0.f};
#pragma unroll
    for (int m = 0; m < 8; ++m) {
      av.x += lo[m] * f[m].x; av.y += lo[m] * f[m].y;
      av.z += lo[m] * f[m].z; av.w += lo[m] * f[m].w;
      dv.x += hi[m] * f[m].x; dv.y += hi[m] * f[m].y;
      dv.z += hi[m] * f[m].z; dv.w += hi[m] * f[m].w;
    }

    // Shift FIFO by 2; issue loads for rows 2i+4, 2i+5 (used 2 iterations
    // from now -> ~2 full stages of latency cover). Reflection keeps the
    // address in-bounds past the segment end.
#pragma unroll
    for (int k = 0; k < 8; ++k) f[k] = f[k + 2];
    f[8] = ldrow(2 * i + 4);
    f[9] = ldrow(2 * i + 5);

    *reinterpret_cast<float4*>(&a_buf[cur][widx]) = av;
    *reinterpret_cast<float4*>(&d_buf[cur][widx]) = dv;

    block_sync_lds();

    // ---- Stage B: horizontal DWT from LDS -> 2 subbands per thread
    if (wr && i < ON) {
      const float* src = sb ? d_buf[cur] : a_buf[cur];
      float4 aL = {0.f, 0.f, 0.f, 0.f}, aH = {0.f, 0.f, 0.f, 0.f};
#pragma unroll
      for (int m = 0; m < 8; ++m) {
        const float4 s = *reinterpret_cast<const float4*>(
            &src[lds_idx(2 * jr + m, bch)]);
        aL.x += lo[m] * s.x; aL.y += lo[m] * s.y;
        aL.z += lo[m] * s.z; aL.w += lo[m] * s.w;
        aH.x += hi[m] * s.x; aH.y += hi[m] * s.y;
        aH.z += hi[m] * s.z; aH.w += hi[m] * s.w;
      }
      const size_t o = (((size_t)b * ON + i) * ON + j) * CH + bch;
      nt_store4(o_lo + o, aL);
      nt_store4(o_hi + o, aH);
    }
  }
}

extern "C" void kernel_launch(void* const* d_in, const int* in_sizes, int n_in,
                              void* d_out, int out_size, void* d_ws, size_t ws_size,
                              hipStream_t stream) {
  const float* x      = (const float*)d_in[0];
  const float* dec_lo = (const float*)d_in[1];
  float* out          = (float*)d_out;
  dim3 grid(BANDS, SEGS, NB);
  dwt2_ring<<<grid, 256, 0, stream>>>(x, dec_lo, out);
}

// Round 8
// 57.164 us; speedup vs baseline: 1.0535x; 1.0119x over previous
//
#include <hip/hip_runtime.h>

// 2-level separable db4 DWT, pywt 'symmetric', fused, rolling-row version v7.
// x: (8, 512, 512, 16) f32 -> out: concat(aa, ad, da, dd), each (8, 259, 259, 16) f32.
//
// v7: minimize ISSUED read traffic (the measured ~6.3 TB/s ceiling is on
// total vector traffic, L3-hit or not): prefetch distance 1 (8-row FIFO,
// warmup 8 rows), last-iteration prefetch elided at compile time.
// 38 rows loaded per block for 32 consumed; 1224 blocks.

constexpr int N  = 512;
constexpr int ON = 259;          // (N + 8 - 1) / 2
constexpr int CH = 16;
constexpr int NB = 8;
constexpr int JB = 29;           // output cols per band
constexpr int BANDS = 9;         // 9*29 = 261 >= 259
constexpr int RS = 16;           // output rows per segment (constant trip)
constexpr int SEGS = 17;         // 17*16 = 272 >= 259
constexpr int W  = 2 * JB + 6;   // 64 input cols per band
constexpr int LSTR = 20;         // padded word stride per column

typedef float vfloat4 __attribute__((ext_vector_type(4)));

__device__ __forceinline__ int refl(int r) {
  r = (r < 0) ? (-r - 1) : r;
  return (r >= N) ? (2 * N - 1 - r) : r;
}

__device__ __forceinline__ int lds_idx(int c, int w) {
  return c * LSTR + ((w + ((c >> 2) << 2)) & 15);
}

// Barrier with LDS-write visibility but WITHOUT draining vmcnt.
__device__ __forceinline__ void block_sync_lds() {
  asm volatile("s_waitcnt lgkmcnt(0)" ::: "memory");
  __builtin_amdgcn_s_barrier();
  __builtin_amdgcn_sched_barrier(0);
}

__device__ __forceinline__ void nt_store4(float* p, float4 v) {
  vfloat4 nv = {v.x, v.y, v.z, v.w};
  __builtin_nontemporal_store(nv, reinterpret_cast<vfloat4*>(p));
}

__global__ __launch_bounds__(256) void dwt2_ring(
    const float* __restrict__ x, const float* __restrict__ dec_lo,
    float* __restrict__ out)
{
  const int band = blockIdx.x, seg = blockIdx.y, b = blockIdx.z;
  const int j0 = band * JB;
  const int i0 = seg * RS;
  const int t  = threadIdx.x;
  const int tc = t >> 2;             // column within band (0..63)
  const int tch = (t & 3) << 2;      // channel word (0,4,8,12)

  __shared__ float a_buf[2][W * LSTR];  // 2 x 5 KB
  __shared__ float d_buf[2][W * LSTR];  // 2 x 5 KB

  float lo[8], hi[8];
#pragma unroll
  for (int m = 0; m < 8; ++m) lo[m] = dec_lo[7 - m];
#pragma unroll
  for (int m = 0; m < 8; ++m) hi[m] = (m & 1) ? -dec_lo[m] : dec_lo[m];

  const int gc = refl(2 * j0 - 6 + tc);
  const float* xb   = x + (size_t)b * N * N * CH;
  const float* colp = xb + (size_t)gc * CH + tch;

  auto ldrow = [&](int r) -> float4 {
    return *reinterpret_cast<const float4*>(colp + (size_t)refl(r) * (N * CH));
  };

  // 8-row register FIFO: f[k] holds input row 2i-6+k.
  float4 f[8];
#pragma unroll
  for (int m = 0; m < 8; ++m) f[m] = ldrow(2 * i0 - 6 + m);

  // Stage-B mapping: threads 0..115 -> aa/ad from a_buf; 116..231 -> da/dd
  // from d_buf; 232..255 idle in stage B.
  const int  sb  = (t >= 116);
  const int  p   = sb ? (t - 116) : t;
  const int  jr  = p >> 2;
  const int  bch = (p & 3) << 2;
  const int  j   = j0 + jr;
  const bool wr  = (t < 232) && (j < ON);
  const size_t OUTSZ = (size_t)NB * ON * ON * CH;
  float* o_lo = out + (size_t)(2 * sb) * OUTSZ;   // aa or da
  float* o_hi = o_lo + OUTSZ;                     // ad or dd

  const int widx = lds_idx(tc, tch);

#pragma unroll
  for (int it = 0; it < RS; ++it) {
    const int i = i0 + it;
    const int cur = it & 1;

    // ---- Stage A: vertical DWT from the register FIFO (rows 2i-6..2i+1)
    float4 av = {0.f, 0.f, 0.f, 0.f}, dv = {0.f, 0.f, 0.f, 0.f};
#pragma unroll
    for (int m = 0; m < 8; ++m) {
      av.x += lo[m] * f[m].x; av.y += lo[m] * f[m].y;
      av.z += lo[m] * f[m].z; av.w += lo[m] * f[m].w;
      dv.x += hi[m] * f[m].x; dv.y += hi[m] * f[m].y;
      dv.z += hi[m] * f[m].z; dv.w += hi[m] * f[m].w;
    }

    // Shift FIFO by 2; issue loads for rows 2i+2, 2i+3 (used next iter).
    // Elided on the last iteration (compile-time under full unroll) —
    // those loads would be dead traffic.
#pragma unroll
    for (int k = 0; k < 6; ++k) f[k] = f[k + 2];
    if (it + 1 < RS) {
      f[6] = ldrow(2 * i + 2);
      f[7] = ldrow(2 * i + 3);
    }

    *reinterpret_cast<float4*>(&a_buf[cur][widx]) = av;
    *reinterpret_cast<float4*>(&d_buf[cur][widx]) = dv;

    block_sync_lds();

    // ---- Stage B: horizontal DWT from LDS -> 2 subbands per thread
    if (wr && i < ON) {
      const float* src = sb ? d_buf[cur] : a_buf[cur];
      float4 aL = {0.f, 0.f, 0.f, 0.f}, aH = {0.f, 0.f, 0.f, 0.f};
#pragma unroll
      for (int m = 0; m < 8; ++m) {
        const float4 s = *reinterpret_cast<const float4*>(
            &src[lds_idx(2 * jr + m, bch)]);
        aL.x += lo[m] * s.x; aL.y += lo[m] * s.y;
        aL.z += lo[m] * s.z; aL.w += lo[m] * s.w;
        aH.x += hi[m] * s.x; aH.y += hi[m] * s.y;
        aH.z += hi[m] * s.z; aH.w += hi[m] * s.w;
      }
      const size_t o = (((size_t)b * ON + i) * ON + j) * CH + bch;
      nt_store4(o_lo + o, aL);
      nt_store4(o_hi + o, aH);
    }
  }
}

extern "C" void kernel_launch(void* const* d_in, const int* in_sizes, int n_in,
                              void* d_out, int out_size, void* d_ws, size_t ws_size,
                              hipStream_t stream) {
  const float* x      = (const float*)d_in[0];
  const float* dec_lo = (const float*)d_in[1];
  float* out          = (float*)d_out;
  dim3 grid(BANDS, SEGS, NB);
  dwt2_ring<<<grid, 256, 0, stream>>>(x, dec_lo, out);
}